// Round 16
// baseline (58.191 us; speedup 1.0000x reference)
//
#include <hip/hip_runtime.h>

// QuantizedConv1d on MI355X (gfx950) — round 16: 4-wave blocks (finer phase
// interleave), same verified per-wave structure.
// B=32, CIN=128, L=4096, COUT=256, K=5, replication pad 2.
//   wprep_kernel: W int32 -> fragment-linear i8 wtf[160][64][16B] + tbl (tiny)
//   conv_fused:   block = 256co x 64l, 256 thr, 4 waves = 4co x 1l,
//                 wave = 64co x 64l (acc[4][4]). Staging: all 32 main loads
//                 upfront; interior tiles skip clamps. i8 MFMA swapped
//                 operands, dwordx4 epilogue (r14/r15-verified).
// Round-15 post-mortem: staging-latency flatten gained only 1us -> staging
// wasn't critical path. 2 barrier domains/CU interleave phases too coarsely;
// 4 blocks/CU doubles the phase offsets covering the HBM pipe.

#define B_    32
#define CIN   128
#define LEN   4096
#define COUT  256
#define KW    5
#define TROWS 72    // staged rows: gl in [l0-4, l0+67]

#define WTF_BYTES (KW * 2 * 16 * 64 * 16)   // 163,840

typedef int          i32x4 __attribute__((ext_vector_type(4)));
typedef signed char  s8;

// round-half-even(x*20 - 3), clip to [-128,127], as int8.
// (fmaf fold vs round(x/0.05)+(-3): ~1e-6 tie flips, <=1 output step each;
// absmax has been 1.0 vs threshold 2.56 since r6.)
__device__ __forceinline__ s8 quant_i8(float xv) {
    float q = rintf(fmaf(xv, 20.0f, -3.0f));
    q = fminf(fmaxf(q, -128.0f), 127.0f);
    return (s8)(int)q;
}

// W -> fragment-linear i8: frag = k*32 + s*16 + co16; lane holds
// W[co16*16 + (lane&15)][ci = s*64 + (lane>>4)*16 + j], j=0..15.
__global__ __launch_bounds__(256) void wprep_kernel(
        const int* __restrict__ w, const int* __restrict__ bias,
        const float* __restrict__ wscale,
        s8* __restrict__ wtf, float* __restrict__ tbl)
{
    int o    = blockIdx.x * 256 + threadIdx.x;   // 0..10239
    int lane = o & 63, frag = o >> 6;            // frag 0..159
    int k    = frag >> 5;
    int s    = (frag >> 4) & 1;
    int co   = ((frag & 15) << 4) + (lane & 15);
    int ci   = (s << 6) + ((lane >> 4) << 4);
    union { s8 c[16]; i32x4 v; } q;
    #pragma unroll
    for (int j = 0; j < 16; ++j)
        q.c[j] = (s8)w[co * (CIN * KW) + (ci + j) * KW + k];   // |v|<=127
    *(i32x4*)(wtf + (size_t)frag * 1024 + lane * 16) = q.v;

    if (blockIdx.x == 0) {                        // requant table: sc, off
        int c = threadIdx.x;                      // 0..255
        float sc = __fdiv_rn(__fmul_rn(0.05f, wscale[c]), 0.1f);
        tbl[c]       = sc;
        tbl[256 + c] = fmaf((float)bias[c], sc, -128.0f);
    }
}

// Block: 256 co x 64 l, 256 threads, 4 waves = 4 co-waves (all share the
// same 64-l range). Wave = 64co x 64l, acc[4][4]. LDS: [72 rows][128 ci] i8
// = 9,216 B, swizzle: 16B-chunk ^= (row & 7) — measured 0 conflicts.
// launch_bounds(256,4): 128-reg cap, 4 blocks/CU = 16 waves, 4 barrier
// domains per CU. Grid 2048 = B(32) x ltile(64), XCD-chunked remap (8x256).
__global__ __launch_bounds__(256, 4) void conv_fused(
        const float* __restrict__ x, const s8* __restrict__ wtf,
        const float* __restrict__ tbl, int* __restrict__ out)
{
    __shared__ __align__(16) s8 smem[TROWS * CIN];   // 9,216 B

    int orig  = (blockIdx.x & 7) * 256 + (blockIdx.x >> 3);
    int ltile = orig & 63;
    int b     = orig >> 6;
    int l0    = ltile << 6;
    int tid   = threadIdx.x;
    int wid   = tid >> 6, lane = tid & 63;
    int lr    = lane & 15, lh = lane >> 4;
    int cog   = wid << 6;                // wave co base: 4 x 64

    const float* xb = x + (size_t)b * CIN * LEN;

    // ---- stage: quantize + transpose rows [l0-4, l0+67] into LDS ----
    // Wave wid owns chunks c0=wid, c1=wid+4 (16 ci each). Rows: lane (0..63)
    // and 64+lane (lane<8). All 32 main loads issued upfront (static arrays).
    {
        bool edge = (ltile == 0) | (ltile == 63);
        const float* src0 = xb + (size_t)(wid << 4) * LEN;
        const float* src1 = xb + (size_t)((wid + 4) << 4) * LEN;
        int gl0 = l0 - 4 + lane;
        if (edge) gl0 = min(max(gl0, 0), LEN - 1);
        float v0[16], v1[16];
        #pragma unroll
        for (int j = 0; j < 16; ++j) v0[j] = src0[(size_t)j * LEN + gl0];
        #pragma unroll
        for (int j = 0; j < 16; ++j) v1[j] = src1[(size_t)j * LEN + gl0];
        union { s8 cc[16]; i32x4 v; } q0, q1;
        #pragma unroll
        for (int j = 0; j < 16; ++j) q0.cc[j] = quant_i8(v0[j]);
        #pragma unroll
        for (int j = 0; j < 16; ++j) q1.cc[j] = quant_i8(v1[j]);
        int row0 = lane;
        int sw0  = (row0 & 7) << 4;
        *(i32x4*)(smem + (row0 << 7) + (((wid) << 4) ^ sw0))     = q0.v;
        *(i32x4*)(smem + (row0 << 7) + (((wid + 4) << 4) ^ sw0)) = q1.v;
        if (lane < 8) {                   // tail rows 64..71
            int row1 = 64 + lane;
            int gl1 = l0 + 60 + lane;
            if (edge) gl1 = min(gl1, LEN - 1);
            union { s8 cc[16]; i32x4 v; } q2, q3;
            #pragma unroll
            for (int j = 0; j < 16; ++j)
                q2.cc[j] = quant_i8(src0[(size_t)j * LEN + gl1]);
            #pragma unroll
            for (int j = 0; j < 16; ++j)
                q3.cc[j] = quant_i8(src1[(size_t)j * LEN + gl1]);
            int sw1 = (row1 & 7) << 4;
            *(i32x4*)(smem + (row1 << 7) + (((wid) << 4) ^ sw1))     = q2.v;
            *(i32x4*)(smem + (row1 << 7) + (((wid + 4) << 4) ^ sw1)) = q3.v;
        }
    }
    __syncthreads();

    // ---- K-loop: 5 taps x 2 ci-halves; 4 af (1KB coalesced, L2-resident) +
    // 4 bf (conflict-free b128) -> 16 mfma_i32_16x16x64_i8.
    // SWAPPED operands (A=X row=l, B=W col=co): D col=co, row=l.
    i32x4 acc[4][4] = {};
    #pragma unroll
    for (int k = 0; k < KW; ++k) {
        #pragma unroll
        for (int s = 0; s < 2; ++s) {
            i32x4 af[4];
            #pragma unroll
            for (int ct = 0; ct < 4; ++ct)
                af[ct] = *(const i32x4*)(
                    wtf + (size_t)((k << 5) + (s << 4) + (cog >> 4) + ct) * 1024 + lane * 16);
            i32x4 bf[4];
            int chunk = (s << 2) + lh;
            #pragma unroll
            for (int lt = 0; lt < 4; ++lt) {
                int row = (lt << 4) + lr + k + 2;
                bf[lt] = *(const i32x4*)(smem + (row << 7) + ((chunk ^ (row & 7)) << 4));
            }
            #pragma unroll
            for (int ct = 0; ct < 4; ++ct)
                #pragma unroll
                for (int lt = 0; lt < 4; ++lt)
                    acc[ct][lt] = __builtin_amdgcn_mfma_i32_16x16x64_i8(
                        bf[lt], af[ct], acc[ct][lt], 0, 0, 0);
        }
    }

    // ---- requant epilogue: col=co=cog+ct*16+lr (per-lane sc/off), row=l.
    // acc[ct][lt] = 4 consecutive l at fixed co -> one dwordx4 store each.
    // (float)int32 is exact (|sum| <= 10.3M < 2^24).
    size_t outb = (size_t)b * COUT * LEN;
    #pragma unroll
    for (int ct = 0; ct < 4; ++ct) {
        int co = cog + (ct << 4) + lr;
        float scv = tbl[co];
        float off = tbl[256 + co];
        int* orow = out + outb + (size_t)co * LEN + l0 + (lh << 2);
        #pragma unroll
        for (int lt = 0; lt < 4; ++lt) {
            i32x4 pk;
            #pragma unroll
            for (int r = 0; r < 4; ++r) {
                float o = rintf(fmaf((float)acc[ct][lt][r], scv, off));
                o = fminf(fmaxf(o, -128.0f), 127.0f);
                pk[r] = (int)o;
            }
            *(i32x4*)(orow + (lt << 4)) = pk;
        }
    }
}

extern "C" void kernel_launch(void* const* d_in, const int* in_sizes, int n_in,
                              void* d_out, int out_size, void* d_ws, size_t ws_size,
                              hipStream_t stream)
{
    const float* x    = (const float*)d_in[0];
    const int*   w    = (const int*)d_in[1];
    const int*   bias = (const int*)d_in[2];
    const float* wsc  = (const float*)d_in[3];
    int* out = (int*)d_out;

    s8*    wtf = (s8*)d_ws;                         // 163,840 B
    float* tbl = (float*)((char*)d_ws + WTF_BYTES); // +2 KB

    wprep_kernel<<<dim3(40), dim3(256), 0, stream>>>(w, bias, wsc, wtf, tbl);
    conv_fused<<<dim3(2048), dim3(256), 0, stream>>>(x, wtf, tbl, out);
}